// Round 3
// baseline (3288.977 us; speedup 1.0000x reference)
//
#include <hip/hip_runtime.h>

// GraphEncoder: node linear; 3x GINEConv(eps=0, nn=Linear+LeakyReLU); skip; head Linear+LayerNorm.
// NOTE: harness delivers integer inputs as int32 -> edge_index is const int*.
// Buffers: h (51.2 MB, in d_ws); sum = d_out doubles as per-layer scratch.
// Skip connection recomputed in the head (x @ W_node staged in LDS).
constexpr int N      = 100000;
constexpr int E      = 1600000;
constexpr int F_IN   = 64;
constexpr int F_EDGE = 16;
constexpr int H      = 128;
constexpr float NEG  = 0.01f;
constexpr float EPS  = 1e-5f;

// ---------------- node linear: h = x @ W_node + b  (4 nodes per 128-channel slot) ----------------
__global__ __launch_bounds__(256) void k_node_linear(
    const float* __restrict__ x, const float* __restrict__ W,
    const float* __restrict__ b, float* __restrict__ h) {
  int tid = blockIdx.x * 256 + threadIdx.x;
  int c = tid & (H - 1);
  int g = tid >> 7;
  int i0 = g * 4;
  if (i0 >= N) return;
  float acc0 = b[c], acc1 = acc0, acc2 = acc0, acc3 = acc0;
#pragma unroll 8
  for (int k = 0; k < F_IN; ++k) {
    float wv = W[k * H + c];                 // coalesced, L1-hot (32 KB)
    acc0 = fmaf(x[(size_t)(i0 + 0) * F_IN + k], wv, acc0);  // wave-uniform -> s_load
    acc1 = fmaf(x[(size_t)(i0 + 1) * F_IN + k], wv, acc1);
    acc2 = fmaf(x[(size_t)(i0 + 2) * F_IN + k], wv, acc2);
    acc3 = fmaf(x[(size_t)(i0 + 3) * F_IN + k], wv, acc3);
  }
  h[(size_t)(i0 + 0) * H + c] = acc0;
  h[(size_t)(i0 + 1) * H + c] = acc1;
  h[(size_t)(i0 + 2) * H + c] = acc2;
  h[(size_t)(i0 + 3) * H + c] = acc3;
}

// ---------------- sum <- h  (vectorized copy; init for edge atomics, folds h+agg) ----------------
__global__ __launch_bounds__(256) void k_copy(
    const float4* __restrict__ src, float4* __restrict__ dst, int n4) {
  int i = blockIdx.x * 256 + threadIdx.x;
  if (i < n4) dst[i] = src[i];
}

// ---------------- edge stage: sum[dst] += relu(h[src] + edge_attr@W_edge + b_edge) ----------------
// One lane = one output channel; W_edge column (16 floats) in registers.
__global__ __launch_bounds__(256) void k_edge(
    const float* __restrict__ edge_attr, const int* __restrict__ eidx,
    const float* __restrict__ We, const float* __restrict__ be,
    const float* __restrict__ h, float* __restrict__ sum) {
  int c = threadIdx.x & (H - 1);
  float w[F_EDGE];
#pragma unroll
  for (int k = 0; k < F_EDGE; ++k) w[k] = We[k * H + c];
  float bias = be[c];
  int slot = (blockIdx.x * 256 + threadIdx.x) >> 7;   // 128 threads per edge-slot
  int nslots = (gridDim.x * 256) >> 7;
  for (int e = slot; e < E; e += nslots) {
    int src = eidx[e];                                 // int32! (harness converts int64)
    int dst = eidx[E + e];
    const float* ar = edge_attr + (size_t)e * F_EDGE;  // wave-uniform -> s_load
    float acc = bias;
#pragma unroll
    for (int k = 0; k < F_EDGE; ++k) acc = fmaf(ar[k], w[k], acc);
    float msg = h[(size_t)src * H + c] + acc;          // gather, L3-resident table
    msg = fmaxf(msg, 0.f);
    atomicAdd(&sum[(size_t)dst * H + c], msg);
  }
}

// ---------------- node update: h = leaky_relu(sum @ W_conv[l] + b)  (in-place on h) ----------------
__global__ __launch_bounds__(256) void k_node_update(
    const float* __restrict__ sum, const float* __restrict__ W,
    const float* __restrict__ b, float* __restrict__ hout) {
  int tid = blockIdx.x * 256 + threadIdx.x;
  int c = tid & (H - 1);
  int g = tid >> 7;
  int i0 = g * 4;
  if (i0 >= N) return;
  float acc0 = b[c], acc1 = acc0, acc2 = acc0, acc3 = acc0;
#pragma unroll 8
  for (int k = 0; k < H; ++k) {
    float wv = W[k * H + c];                 // coalesced; reused by 4 nodes
    acc0 = fmaf(sum[(size_t)(i0 + 0) * H + k], wv, acc0);
    acc1 = fmaf(sum[(size_t)(i0 + 1) * H + k], wv, acc1);
    acc2 = fmaf(sum[(size_t)(i0 + 2) * H + k], wv, acc2);
    acc3 = fmaf(sum[(size_t)(i0 + 3) * H + k], wv, acc3);
  }
  hout[(size_t)(i0 + 0) * H + c] = acc0 >= 0.f ? acc0 : NEG * acc0;
  hout[(size_t)(i0 + 1) * H + c] = acc1 >= 0.f ? acc1 : NEG * acc1;
  hout[(size_t)(i0 + 2) * H + c] = acc2 >= 0.f ? acc2 : NEG * acc2;
  hout[(size_t)(i0 + 3) * H + c] = acc3 >= 0.f ? acc3 : NEG * acc3;
}

// ---------------- head: skip = x@W_node+b (recomputed, LDS); y = (skip+h)@W_head + b; LayerNorm ----------------
__global__ __launch_bounds__(128) void k_head(
    const float* __restrict__ x, const float* __restrict__ Wn,
    const float* __restrict__ bn, const float* __restrict__ hfin,
    const float* __restrict__ W, const float* __restrict__ b,
    const float* __restrict__ gamma, const float* __restrict__ beta,
    float* __restrict__ out) {
  int c = threadIdx.x;
  int i0 = blockIdx.x * 4;
  __shared__ float t[4][H];                  // skip + h_final, staged for the K-loop
#pragma unroll
  for (int j = 0; j < 4; ++j) {
    float a = bn[c];
#pragma unroll 8
    for (int k = 0; k < F_IN; ++k)
      a = fmaf(x[(size_t)(i0 + j) * F_IN + k], Wn[k * H + c], a);  // x: wave-uniform
    t[j][c] = a + hfin[(size_t)(i0 + j) * H + c];
  }
  __syncthreads();
  float bc = b[c];
  float acc[4] = {bc, bc, bc, bc};
#pragma unroll 8
  for (int k = 0; k < H; ++k) {
    float wv = W[k * H + c];
#pragma unroll
    for (int j = 0; j < 4; ++j) acc[j] = fmaf(t[k & 3][0] * 0.f + t[j][k], wv, acc[j]);
  }
  __shared__ float ls[2][4], ls2[2][4];
  int wid = c >> 6;
#pragma unroll
  for (int j = 0; j < 4; ++j) {
    float s = acc[j], s2 = acc[j] * acc[j];
#pragma unroll
    for (int off = 32; off > 0; off >>= 1) {
      s  += __shfl_down(s, off, 64);
      s2 += __shfl_down(s2, off, 64);
    }
    if ((c & 63) == 0) { ls[wid][j] = s; ls2[wid][j] = s2; }
  }
  __syncthreads();
#pragma unroll
  for (int j = 0; j < 4; ++j) {
    float S  = ls[0][j] + ls[1][j];
    float S2 = ls2[0][j] + ls2[1][j];
    float mu  = S * (1.f / H);
    float var = S2 * (1.f / H) - mu * mu;
    float inv = rsqrtf(var + EPS);
    out[(size_t)(i0 + j) * H + c] = (acc[j] - mu) * inv * gamma[c] + beta[c];
  }
}

extern "C" void kernel_launch(void* const* d_in, const int* in_sizes, int n_in,
                              void* d_out, int out_size, void* d_ws, size_t ws_size,
                              hipStream_t stream) {
  const float* x         = (const float*)d_in[0];
  const float* edge_attr = (const float*)d_in[1];
  const int*   eidx      = (const int*)d_in[2];      // int32 per harness conversion
  const float* W_node    = (const float*)d_in[3];
  const float* b_node    = (const float*)d_in[4];
  const float* W_edge    = (const float*)d_in[5];
  const float* b_edge    = (const float*)d_in[6];
  const float* W_conv    = (const float*)d_in[7];    // [3,128,128]
  const float* b_conv    = (const float*)d_in[8];    // [3,128]
  const float* W_head    = (const float*)d_in[9];
  const float* b_head    = (const float*)d_in[10];
  const float* gamma     = (const float*)d_in[11];
  const float* beta      = (const float*)d_in[12];
  float* out = (float*)d_out;

  size_t S = (size_t)N * H;                  // 12.8M floats = 51.2 MB
  float* h   = (float*)d_ws;                 // only ws use: 51.2 MB
  float* sum = out;                          // d_out doubles as layer scratch

  const int matvec_blocks = (N / 4) * H / 256;   // 12500
  const int copy_blocks   = (int)(S / 4 / 256);  // 12500

  k_node_linear<<<matvec_blocks, 256, 0, stream>>>(x, W_node, b_node, h);

  for (int l = 0; l < 3; ++l) {
    k_copy<<<copy_blocks, 256, 0, stream>>>((const float4*)h, (float4*)sum, (int)(S / 4));
    k_edge<<<8192, 256, 0, stream>>>(edge_attr, eidx, W_edge, b_edge, h, sum);
    k_node_update<<<matvec_blocks, 256, 0, stream>>>(
        sum, W_conv + (size_t)l * H * H, b_conv + (size_t)l * H, h);
  }

  k_head<<<N / 4, 128, 0, stream>>>(x, W_node, b_node, h, W_head, b_head, gamma, beta, out);
}

// Round 4
// 2317.045 us; speedup vs baseline: 1.4195x; 1.4195x over previous
//
#include <hip/hip_runtime.h>

// GraphEncoder: node linear; 3x GINEConv(eps=0, nn=Linear+LeakyReLU); skip; head Linear+LayerNorm.
// R4: device-built CSR (histogram+scan+scatter) -> atomic-free gather-accumulate edge stage.
//     LDS-staged activation rows in the matvec kernels (broadcast reads instead of
//     64-lanes-same-address global loads).
// edge_index arrives as int32 (harness converts int64 inputs).
constexpr int N      = 100000;
constexpr int E      = 1600000;
constexpr int F_IN   = 64;
constexpr int F_EDGE = 16;
constexpr int H      = 128;
constexpr int NB     = (N + 255) / 256;     // 391 scan blocks
constexpr float NEG  = 0.01f;
constexpr float EPS  = 1e-5f;

// ================= CSR build =================
__global__ __launch_bounds__(256) void k_zero(int* __restrict__ p, int n) {
  int i = blockIdx.x * 256 + threadIdx.x;
  if (i < n) p[i] = 0;
}

__global__ __launch_bounds__(256) void k_hist(const int* __restrict__ eidx, int* __restrict__ deg) {
  int i = blockIdx.x * 256 + threadIdx.x;
  if (i < E) atomicAdd(&deg[eidx[E + i]], 1);
}

__global__ __launch_bounds__(256) void k_scan_block(const int* __restrict__ deg,
    int* __restrict__ excl, int* __restrict__ bsum) {
  __shared__ int s[256];
  int t = threadIdx.x, i = blockIdx.x * 256 + t;
  int v = (i < N) ? deg[i] : 0;
  s[t] = v; __syncthreads();
#pragma unroll
  for (int off = 1; off < 256; off <<= 1) {
    int u = (t >= off) ? s[t - off] : 0;
    __syncthreads();
    s[t] += u;
    __syncthreads();
  }
  if (i < N) excl[i] = s[t] - v;
  if (t == 255) bsum[blockIdx.x] = s[255];
}

__global__ __launch_bounds__(512) void k_scan_top(const int* __restrict__ bsum, int* __restrict__ boff) {
  __shared__ int s[512];
  int t = threadIdx.x;
  int v = (t < NB) ? bsum[t] : 0;
  s[t] = v; __syncthreads();
#pragma unroll
  for (int off = 1; off < 512; off <<= 1) {
    int u = (t >= off) ? s[t - off] : 0;
    __syncthreads();
    s[t] += u;
    __syncthreads();
  }
  if (t < NB) boff[t] = s[t] - v;
}

__global__ __launch_bounds__(256) void k_scan_add(const int* __restrict__ excl,
    const int* __restrict__ boff, int* __restrict__ rowptr, int* __restrict__ cursor) {
  int i = blockIdx.x * 256 + threadIdx.x;
  if (i < N) {
    int r = excl[i] + boff[i >> 8];
    rowptr[i] = r;
    cursor[i] = r;
  }
}

__global__ __launch_bounds__(256) void k_scatter(const int* __restrict__ eidx,
    int* __restrict__ cursor, int2* __restrict__ csr_se) {
  int i = blockIdx.x * 256 + threadIdx.x;
  if (i < E) {
    int d = eidx[E + i];
    int pos = atomicAdd(&cursor[d], 1);
    csr_se[pos] = make_int2(eidx[i], i);   // (src, edge_id)
  }
}

// ================= node linear: h = x @ W_node + b  (8 nodes / 256-thread block) =================
__global__ __launch_bounds__(256) void k_node_linear(
    const float* __restrict__ x, const float* __restrict__ W,
    const float* __restrict__ b, float* __restrict__ h) {
  __shared__ float xs[8][F_IN];              // 2 KB
  int i0 = blockIdx.x * 8;
  ((float2*)xs)[threadIdx.x] = ((const float2*)(x + (size_t)i0 * F_IN))[threadIdx.x];
  __syncthreads();
  int c = threadIdx.x & (H - 1);
  int j0 = (threadIdx.x >> 7) * 4;           // 0 or 4
  float bc = b[c];
  float acc[4] = {bc, bc, bc, bc};
#pragma unroll 8
  for (int k = 0; k < F_IN; ++k) {
    float wv = W[k * H + c];                 // coalesced, L1-hot
#pragma unroll
    for (int j = 0; j < 4; ++j) acc[j] = fmaf(xs[j0 + j][k], wv, acc[j]);  // LDS broadcast
  }
#pragma unroll
  for (int j = 0; j < 4; ++j) h[(size_t)(i0 + j0 + j) * H + c] = acc[j];
}

// ================= gather: sum[i] = h[i] + sum_in relu(h[src] + edge_attr@We + be) =================
// One node per 128-thread group (2 waves); lane = channel; We column in registers.
__global__ __launch_bounds__(256) void k_gather(
    const int* __restrict__ rowptr, const int* __restrict__ deg,
    const int2* __restrict__ csr_se, const float* __restrict__ edge_attr,
    const float* __restrict__ We, const float* __restrict__ be,
    const float* __restrict__ h, float* __restrict__ sum) {
  int c = threadIdx.x & (H - 1);
  int node = (blockIdx.x * 256 + threadIdx.x) >> 7;
  if (node >= N) return;
  float w[F_EDGE];
#pragma unroll
  for (int k = 0; k < F_EDGE; ++k) w[k] = We[k * H + c];
  float bias = be[c];
  int p0 = rowptr[node], d = deg[node];
  float acc = h[(size_t)node * H + c];
  for (int p = p0; p < p0 + d; ++p) {
    int2 se = csr_se[p];                     // wave-uniform
    const float* ar = edge_attr + (size_t)se.y * F_EDGE;
    float t = bias;
#pragma unroll
    for (int k = 0; k < F_EDGE; ++k) t = fmaf(ar[k], w[k], t);
    float m = h[(size_t)se.x * H + c] + t;   // coalesced 512B gather, L2/L3-resident
    acc += fmaxf(m, 0.f);
  }
  sum[(size_t)node * H + c] = acc;
}

// ================= node update: h = leaky_relu(sum @ W_conv[l] + b)  (8 nodes / block) =================
__global__ __launch_bounds__(256) void k_node_update(
    const float* __restrict__ sum, const float* __restrict__ W,
    const float* __restrict__ b, float* __restrict__ hout) {
  __shared__ float t[8][H];                  // 4 KB
  int i0 = blockIdx.x * 8;
  // stage 8 rows (4 KB) cooperatively: 256 threads x float4
  ((float4*)t)[threadIdx.x] = ((const float4*)(sum + (size_t)i0 * H))[threadIdx.x];
  __syncthreads();
  int c = threadIdx.x & (H - 1);
  int j0 = (threadIdx.x >> 7) * 4;
  float bc = b[c];
  float acc[4] = {bc, bc, bc, bc};
#pragma unroll 8
  for (int k = 0; k < H; ++k) {
    float wv = W[k * H + c];                 // coalesced, L1/L2-hot (64 KB)
#pragma unroll
    for (int j = 0; j < 4; ++j) acc[j] = fmaf(t[j0 + j][k], wv, acc[j]);  // LDS broadcast
  }
#pragma unroll
  for (int j = 0; j < 4; ++j) {
    float a = acc[j];
    hout[(size_t)(i0 + j0 + j) * H + c] = a >= 0.f ? a : NEG * a;
  }
}

// ================= head: skip recomputed; y = (skip+h)@W_head + b; LayerNorm =================
__global__ __launch_bounds__(128) void k_head(
    const float* __restrict__ x, const float* __restrict__ Wn,
    const float* __restrict__ bn, const float* __restrict__ hfin,
    const float* __restrict__ W, const float* __restrict__ b,
    const float* __restrict__ gamma, const float* __restrict__ beta,
    float* __restrict__ out) {
  int c = threadIdx.x;
  int i0 = blockIdx.x * 4;
  __shared__ float xs[4][F_IN];              // 1 KB
  __shared__ float t[4][H];                  // 2 KB
  ((float2*)xs)[threadIdx.x] = ((const float2*)(x + (size_t)i0 * F_IN))[threadIdx.x];
  __syncthreads();
#pragma unroll
  for (int j = 0; j < 4; ++j) {
    float a = bn[c];
#pragma unroll 8
    for (int k = 0; k < F_IN; ++k) a = fmaf(xs[j][k], Wn[k * H + c], a);  // LDS broadcast
    t[j][c] = a + hfin[(size_t)(i0 + j) * H + c];
  }
  __syncthreads();
  float bc = b[c];
  float acc[4] = {bc, bc, bc, bc};
#pragma unroll 8
  for (int k = 0; k < H; ++k) {
    float wv = W[k * H + c];
#pragma unroll
    for (int j = 0; j < 4; ++j) acc[j] = fmaf(t[j][k], wv, acc[j]);
  }
  __shared__ float ls[2][4], ls2[2][4];
  int wid = c >> 6;
#pragma unroll
  for (int j = 0; j < 4; ++j) {
    float s = acc[j], s2 = acc[j] * acc[j];
#pragma unroll
    for (int off = 32; off > 0; off >>= 1) {
      s  += __shfl_down(s, off, 64);
      s2 += __shfl_down(s2, off, 64);
    }
    if ((c & 63) == 0) { ls[wid][j] = s; ls2[wid][j] = s2; }
  }
  __syncthreads();
#pragma unroll
  for (int j = 0; j < 4; ++j) {
    float S  = ls[0][j] + ls[1][j];
    float S2 = ls2[0][j] + ls2[1][j];
    float mu  = S * (1.f / H);
    float var = S2 * (1.f / H) - mu * mu;
    float inv = rsqrtf(var + EPS);
    out[(size_t)(i0 + j) * H + c] = (acc[j] - mu) * inv * gamma[c] + beta[c];
  }
}

extern "C" void kernel_launch(void* const* d_in, const int* in_sizes, int n_in,
                              void* d_out, int out_size, void* d_ws, size_t ws_size,
                              hipStream_t stream) {
  const float* x         = (const float*)d_in[0];
  const float* edge_attr = (const float*)d_in[1];
  const int*   eidx      = (const int*)d_in[2];      // int32 (harness-converted)
  const float* W_node    = (const float*)d_in[3];
  const float* b_node    = (const float*)d_in[4];
  const float* W_edge    = (const float*)d_in[5];
  const float* b_edge    = (const float*)d_in[6];
  const float* W_conv    = (const float*)d_in[7];    // [3,128,128]
  const float* b_conv    = (const float*)d_in[8];    // [3,128]
  const float* W_head    = (const float*)d_in[9];
  const float* b_head    = (const float*)d_in[10];
  const float* gamma     = (const float*)d_in[11];
  const float* beta      = (const float*)d_in[12];
  float* out = (float*)d_out;

  // ---- workspace layout (~66 MB) ----
  size_t S = (size_t)N * H;                  // 12.8M floats = 51.2 MB
  float* h      = (float*)d_ws;
  int*   deg    = (int*)(h + S);
  int*   excl   = deg + N;
  int*   rowptr = excl + N;
  int*   cursor = rowptr + N;
  int*   bsum   = cursor + N;
  int*   boff   = bsum + 512;
  int2*  csr_se = (int2*)(boff + 512);       // 12.8 MB
  float* sum    = out;                       // d_out doubles as layer scratch

  const int eb = (E + 255) / 256;            // 6250

  // ---- CSR build (once; dst fixed across layers) ----
  k_zero<<<NB, 256, 0, stream>>>(deg, N);
  k_hist<<<eb, 256, 0, stream>>>(eidx, deg);
  k_scan_block<<<NB, 256, 0, stream>>>(deg, excl, bsum);
  k_scan_top<<<1, 512, 0, stream>>>(bsum, boff);
  k_scan_add<<<NB, 256, 0, stream>>>(excl, boff, rowptr, cursor);
  k_scatter<<<eb, 256, 0, stream>>>(eidx, cursor, csr_se);

  // ---- network ----
  k_node_linear<<<N / 8, 256, 0, stream>>>(x, W_node, b_node, h);

  for (int l = 0; l < 3; ++l) {
    k_gather<<<(N + 1) / 2, 256, 0, stream>>>(rowptr, deg, csr_se, edge_attr,
                                              W_edge, b_edge, h, sum);
    k_node_update<<<N / 8, 256, 0, stream>>>(
        sum, W_conv + (size_t)l * H * H, b_conv + (size_t)l * H, h);
  }

  k_head<<<N / 4, 128, 0, stream>>>(x, W_node, b_node, h, W_head, b_head, gamma, beta, out);
}

// Round 5
// 2154.936 us; speedup vs baseline: 1.5263x; 1.0752x over previous
//
#include <hip/hip_runtime.h>

// GraphEncoder: node linear; 3x GINEConv(eps=0, nn=Linear+LeakyReLU); skip; head Linear+LayerNorm.
// R5: k_gather unrolled x4 -> 4 gathers + 4 edge_attr rows in flight per wave
//     (R4 was latency-bound: 28% VALUBusy, 12% HBM, serial load->load chain).
// edge_index arrives as int32 (harness converts int64 inputs).
constexpr int N      = 100000;
constexpr int E      = 1600000;
constexpr int F_IN   = 64;
constexpr int F_EDGE = 16;
constexpr int H      = 128;
constexpr int NB     = (N + 255) / 256;     // 391 scan blocks
constexpr float NEG  = 0.01f;
constexpr float EPS  = 1e-5f;

// ================= CSR build =================
__global__ __launch_bounds__(256) void k_zero(int* __restrict__ p, int n) {
  int i = blockIdx.x * 256 + threadIdx.x;
  if (i < n) p[i] = 0;
}

__global__ __launch_bounds__(256) void k_hist(const int* __restrict__ eidx, int* __restrict__ deg) {
  int i = blockIdx.x * 256 + threadIdx.x;
  if (i < E) atomicAdd(&deg[eidx[E + i]], 1);
}

__global__ __launch_bounds__(256) void k_scan_block(const int* __restrict__ deg,
    int* __restrict__ excl, int* __restrict__ bsum) {
  __shared__ int s[256];
  int t = threadIdx.x, i = blockIdx.x * 256 + t;
  int v = (i < N) ? deg[i] : 0;
  s[t] = v; __syncthreads();
#pragma unroll
  for (int off = 1; off < 256; off <<= 1) {
    int u = (t >= off) ? s[t - off] : 0;
    __syncthreads();
    s[t] += u;
    __syncthreads();
  }
  if (i < N) excl[i] = s[t] - v;
  if (t == 255) bsum[blockIdx.x] = s[255];
}

__global__ __launch_bounds__(512) void k_scan_top(const int* __restrict__ bsum, int* __restrict__ boff) {
  __shared__ int s[512];
  int t = threadIdx.x;
  int v = (t < NB) ? bsum[t] : 0;
  s[t] = v; __syncthreads();
#pragma unroll
  for (int off = 1; off < 512; off <<= 1) {
    int u = (t >= off) ? s[t - off] : 0;
    __syncthreads();
    s[t] += u;
    __syncthreads();
  }
  if (t < NB) boff[t] = s[t] - v;
}

__global__ __launch_bounds__(256) void k_scan_add(const int* __restrict__ excl,
    const int* __restrict__ boff, int* __restrict__ rowptr, int* __restrict__ cursor) {
  int i = blockIdx.x * 256 + threadIdx.x;
  if (i < N) {
    int r = excl[i] + boff[i >> 8];
    rowptr[i] = r;
    cursor[i] = r;
  }
}

__global__ __launch_bounds__(256) void k_scatter(const int* __restrict__ eidx,
    int* __restrict__ cursor, int2* __restrict__ csr_se) {
  int i = blockIdx.x * 256 + threadIdx.x;
  if (i < E) {
    int d = eidx[E + i];
    int pos = atomicAdd(&cursor[d], 1);
    csr_se[pos] = make_int2(eidx[i], i);   // (src, edge_id)
  }
}

// ================= node linear: h = x @ W_node + b  (8 nodes / 256-thread block) =================
__global__ __launch_bounds__(256) void k_node_linear(
    const float* __restrict__ x, const float* __restrict__ W,
    const float* __restrict__ b, float* __restrict__ h) {
  __shared__ float xs[8][F_IN];              // 2 KB
  int i0 = blockIdx.x * 8;
  ((float2*)xs)[threadIdx.x] = ((const float2*)(x + (size_t)i0 * F_IN))[threadIdx.x];
  __syncthreads();
  int c = threadIdx.x & (H - 1);
  int j0 = (threadIdx.x >> 7) * 4;           // 0 or 4
  float bc = b[c];
  float acc[4] = {bc, bc, bc, bc};
#pragma unroll 8
  for (int k = 0; k < F_IN; ++k) {
    float wv = W[k * H + c];                 // coalesced, L1-hot
#pragma unroll
    for (int j = 0; j < 4; ++j) acc[j] = fmaf(xs[j0 + j][k], wv, acc[j]);  // LDS broadcast
  }
#pragma unroll
  for (int j = 0; j < 4; ++j) h[(size_t)(i0 + j0 + j) * H + c] = acc[j];
}

// ================= gather: sum[i] = h[i] + sum_in relu(h[src] + edge_attr@We + be) =================
// One node per 128-thread group; lane = channel; We column in registers.
// Edge loop unrolled x4: 4 h-gathers + 4 attr rows in flight (MLP vs R4's serial chain).
__global__ __launch_bounds__(256) void k_gather(
    const int* __restrict__ rowptr, const int* __restrict__ deg,
    const int2* __restrict__ csr_se, const float* __restrict__ edge_attr,
    const float* __restrict__ We, const float* __restrict__ be,
    const float* __restrict__ h, float* __restrict__ sum) {
  int c = threadIdx.x & (H - 1);
  int node = (blockIdx.x * 256 + threadIdx.x) >> 7;
  if (node >= N) return;
  float w[F_EDGE];
#pragma unroll
  for (int k = 0; k < F_EDGE; ++k) w[k] = We[k * H + c];
  float bias = be[c];
  int p0 = rowptr[node];
  int pend = p0 + deg[node];
  float acc = h[(size_t)node * H + c];
  int p = p0;
  for (; p + 4 <= pend; p += 4) {
    int2 se0 = csr_se[p + 0];                // sequential -> L1-hot, merged loads
    int2 se1 = csr_se[p + 1];
    int2 se2 = csr_se[p + 2];
    int2 se3 = csr_se[p + 3];
    float g0 = h[(size_t)se0.x * H + c];     // 4 independent 512B gathers in flight
    float g1 = h[(size_t)se1.x * H + c];
    float g2 = h[(size_t)se2.x * H + c];
    float g3 = h[(size_t)se3.x * H + c];
    const float* a0 = edge_attr + (size_t)se0.y * F_EDGE;   // wave-uniform rows
    const float* a1 = edge_attr + (size_t)se1.y * F_EDGE;
    const float* a2 = edge_attr + (size_t)se2.y * F_EDGE;
    const float* a3 = edge_attr + (size_t)se3.y * F_EDGE;
    float t0 = bias, t1 = bias, t2 = bias, t3 = bias;
#pragma unroll
    for (int k = 0; k < F_EDGE; ++k) {
      t0 = fmaf(a0[k], w[k], t0);
      t1 = fmaf(a1[k], w[k], t1);
      t2 = fmaf(a2[k], w[k], t2);
      t3 = fmaf(a3[k], w[k], t3);
    }
    acc += fmaxf(g0 + t0, 0.f) + fmaxf(g1 + t1, 0.f)
         + fmaxf(g2 + t2, 0.f) + fmaxf(g3 + t3, 0.f);
  }
  for (; p < pend; ++p) {
    int2 se = csr_se[p];
    const float* ar = edge_attr + (size_t)se.y * F_EDGE;
    float t = bias;
#pragma unroll
    for (int k = 0; k < F_EDGE; ++k) t = fmaf(ar[k], w[k], t);
    acc += fmaxf(h[(size_t)se.x * H + c] + t, 0.f);
  }
  sum[(size_t)node * H + c] = acc;
}

// ================= node update: h = leaky_relu(sum @ W_conv[l] + b)  (8 nodes / block) =================
__global__ __launch_bounds__(256) void k_node_update(
    const float* __restrict__ sum, const float* __restrict__ W,
    const float* __restrict__ b, float* __restrict__ hout) {
  __shared__ float t[8][H];                  // 4 KB
  int i0 = blockIdx.x * 8;
  ((float4*)t)[threadIdx.x] = ((const float4*)(sum + (size_t)i0 * H))[threadIdx.x];
  __syncthreads();
  int c = threadIdx.x & (H - 1);
  int j0 = (threadIdx.x >> 7) * 4;
  float bc = b[c];
  float acc[4] = {bc, bc, bc, bc};
#pragma unroll 8
  for (int k = 0; k < H; ++k) {
    float wv = W[k * H + c];                 // coalesced, L1/L2-hot (64 KB)
#pragma unroll
    for (int j = 0; j < 4; ++j) acc[j] = fmaf(t[j0 + j][k], wv, acc[j]);  // LDS broadcast
  }
#pragma unroll
  for (int j = 0; j < 4; ++j) {
    float a = acc[j];
    hout[(size_t)(i0 + j0 + j) * H + c] = a >= 0.f ? a : NEG * a;
  }
}

// ================= head: skip recomputed; y = (skip+h)@W_head + b; LayerNorm =================
__global__ __launch_bounds__(128) void k_head(
    const float* __restrict__ x, const float* __restrict__ Wn,
    const float* __restrict__ bn, const float* __restrict__ hfin,
    const float* __restrict__ W, const float* __restrict__ b,
    const float* __restrict__ gamma, const float* __restrict__ beta,
    float* __restrict__ out) {
  int c = threadIdx.x;
  int i0 = blockIdx.x * 4;
  __shared__ float xs[4][F_IN];              // 1 KB
  __shared__ float t[4][H];                  // 2 KB
  ((float2*)xs)[threadIdx.x] = ((const float2*)(x + (size_t)i0 * F_IN))[threadIdx.x];
  __syncthreads();
#pragma unroll
  for (int j = 0; j < 4; ++j) {
    float a = bn[c];
#pragma unroll 8
    for (int k = 0; k < F_IN; ++k) a = fmaf(xs[j][k], Wn[k * H + c], a);  // LDS broadcast
    t[j][c] = a + hfin[(size_t)(i0 + j) * H + c];
  }
  __syncthreads();
  float bc = b[c];
  float acc[4] = {bc, bc, bc, bc};
#pragma unroll 8
  for (int k = 0; k < H; ++k) {
    float wv = W[k * H + c];
#pragma unroll
    for (int j = 0; j < 4; ++j) acc[j] = fmaf(t[j][k], wv, acc[j]);
  }
  __shared__ float ls[2][4], ls2[2][4];
  int wid = c >> 6;
#pragma unroll
  for (int j = 0; j < 4; ++j) {
    float s = acc[j], s2 = acc[j] * acc[j];
#pragma unroll
    for (int off = 32; off > 0; off >>= 1) {
      s  += __shfl_down(s, off, 64);
      s2 += __shfl_down(s2, off, 64);
    }
    if ((c & 63) == 0) { ls[wid][j] = s; ls2[wid][j] = s2; }
  }
  __syncthreads();
#pragma unroll
  for (int j = 0; j < 4; ++j) {
    float S  = ls[0][j] + ls[1][j];
    float S2 = ls2[0][j] + ls2[1][j];
    float mu  = S * (1.f / H);
    float var = S2 * (1.f / H) - mu * mu;
    float inv = rsqrtf(var + EPS);
    out[(size_t)(i0 + j) * H + c] = (acc[j] - mu) * inv * gamma[c] + beta[c];
  }
}

extern "C" void kernel_launch(void* const* d_in, const int* in_sizes, int n_in,
                              void* d_out, int out_size, void* d_ws, size_t ws_size,
                              hipStream_t stream) {
  const float* x         = (const float*)d_in[0];
  const float* edge_attr = (const float*)d_in[1];
  const int*   eidx      = (const int*)d_in[2];      // int32 (harness-converted)
  const float* W_node    = (const float*)d_in[3];
  const float* b_node    = (const float*)d_in[4];
  const float* W_edge    = (const float*)d_in[5];
  const float* b_edge    = (const float*)d_in[6];
  const float* W_conv    = (const float*)d_in[7];    // [3,128,128]
  const float* b_conv    = (const float*)d_in[8];    // [3,128]
  const float* W_head    = (const float*)d_in[9];
  const float* b_head    = (const float*)d_in[10];
  const float* gamma     = (const float*)d_in[11];
  const float* beta      = (const float*)d_in[12];
  float* out = (float*)d_out;

  // ---- workspace layout (~66 MB) ----
  size_t S = (size_t)N * H;                  // 12.8M floats = 51.2 MB
  float* h      = (float*)d_ws;
  int*   deg    = (int*)(h + S);
  int*   excl   = deg + N;
  int*   rowptr = excl + N;
  int*   cursor = rowptr + N;
  int*   bsum   = cursor + N;
  int*   boff   = bsum + 512;
  int2*  csr_se = (int2*)(boff + 512);       // 12.8 MB
  float* sum    = out;                       // d_out doubles as layer scratch

  const int eb = (E + 255) / 256;            // 6250

  // ---- CSR build (once; dst fixed across layers) ----
  k_zero<<<NB, 256, 0, stream>>>(deg, N);
  k_hist<<<eb, 256, 0, stream>>>(eidx, deg);
  k_scan_block<<<NB, 256, 0, stream>>>(deg, excl, bsum);
  k_scan_top<<<1, 512, 0, stream>>>(bsum, boff);
  k_scan_add<<<NB, 256, 0, stream>>>(excl, boff, rowptr, cursor);
  k_scatter<<<eb, 256, 0, stream>>>(eidx, cursor, csr_se);

  // ---- network ----
  k_node_linear<<<N / 8, 256, 0, stream>>>(x, W_node, b_node, h);

  for (int l = 0; l < 3; ++l) {
    k_gather<<<(N + 1) / 2, 256, 0, stream>>>(rowptr, deg, csr_se, edge_attr,
                                              W_edge, b_edge, h, sum);
    k_node_update<<<N / 8, 256, 0, stream>>>(
        sum, W_conv + (size_t)l * H * H, b_conv + (size_t)l * H, h);
  }

  k_head<<<N / 4, 128, 0, stream>>>(x, W_node, b_node, h, W_head, b_head, gamma, beta, out);
}

// Round 6
// 1317.673 us; speedup vs baseline: 2.4961x; 1.6354x over previous
//
#include <hip/hip_runtime.h>
#include <hip/hip_fp16.h>

// GraphEncoder: node linear; 3x GINEConv(eps=0, nn=Linear+LeakyReLU); skip; head Linear+LayerNorm.
// R6: gather is line-fill-rate bound past L2 (R5: 8M lines/528us ~= 0.8 lines/cyc/XCD).
//     -> fp16 message table h16 (halves random h lines), fp16 edge attrs packed into CSR
//        (random attr lines -> sequential stream), 1 wave per node (lane = 2 channels).
// edge_index arrives as int32 (harness converts int64 inputs).
constexpr int N      = 100000;
constexpr int E      = 1600000;
constexpr int F_IN   = 64;
constexpr int F_EDGE = 16;
constexpr int H      = 128;
constexpr int NB     = (N + 255) / 256;     // 391 scan blocks
constexpr float NEG  = 0.01f;
constexpr float EPS  = 1e-5f;

// ================= CSR build =================
__global__ __launch_bounds__(256) void k_zero(int* __restrict__ p, int n) {
  int i = blockIdx.x * 256 + threadIdx.x;
  if (i < n) p[i] = 0;
}

__global__ __launch_bounds__(256) void k_hist(const int* __restrict__ eidx, int* __restrict__ deg) {
  int i = blockIdx.x * 256 + threadIdx.x;
  if (i < E) atomicAdd(&deg[eidx[E + i]], 1);
}

__global__ __launch_bounds__(256) void k_scan_block(const int* __restrict__ deg,
    int* __restrict__ excl, int* __restrict__ bsum) {
  __shared__ int s[256];
  int t = threadIdx.x, i = blockIdx.x * 256 + t;
  int v = (i < N) ? deg[i] : 0;
  s[t] = v; __syncthreads();
#pragma unroll
  for (int off = 1; off < 256; off <<= 1) {
    int u = (t >= off) ? s[t - off] : 0;
    __syncthreads();
    s[t] += u;
    __syncthreads();
  }
  if (i < N) excl[i] = s[t] - v;
  if (t == 255) bsum[blockIdx.x] = s[255];
}

__global__ __launch_bounds__(512) void k_scan_top(const int* __restrict__ bsum, int* __restrict__ boff) {
  __shared__ int s[512];
  int t = threadIdx.x;
  int v = (t < NB) ? bsum[t] : 0;
  s[t] = v; __syncthreads();
#pragma unroll
  for (int off = 1; off < 512; off <<= 1) {
    int u = (t >= off) ? s[t - off] : 0;
    __syncthreads();
    s[t] += u;
    __syncthreads();
  }
  if (t < NB) boff[t] = s[t] - v;
}

__global__ __launch_bounds__(256) void k_scan_add(const int* __restrict__ excl,
    const int* __restrict__ boff, int* __restrict__ rowptr, int* __restrict__ cursor) {
  int i = blockIdx.x * 256 + threadIdx.x;
  if (i < N) {
    int r = excl[i] + boff[i >> 8];
    rowptr[i] = r;
    cursor[i] = r;
  }
}

// scatter: CSR-slot src index + edge_attr row converted to fp16 (2x uint4 = 32B/edge)
__global__ __launch_bounds__(256) void k_scatter(const int* __restrict__ eidx,
    const float* __restrict__ edge_attr, int* __restrict__ cursor,
    int* __restrict__ csr_src, uint4* __restrict__ csr_a16) {
  int i = blockIdx.x * 256 + threadIdx.x;
  if (i >= E) return;
  int d = eidx[E + i];
  int pos = atomicAdd(&cursor[d], 1);
  csr_src[pos] = eidx[i];
  const float4* ar = (const float4*)(edge_attr + (size_t)i * F_EDGE);
  float4 f0 = ar[0], f1 = ar[1], f2 = ar[2], f3 = ar[3];
  __half2 hh[8];
  hh[0] = __float22half2_rn(make_float2(f0.x, f0.y));
  hh[1] = __float22half2_rn(make_float2(f0.z, f0.w));
  hh[2] = __float22half2_rn(make_float2(f1.x, f1.y));
  hh[3] = __float22half2_rn(make_float2(f1.z, f1.w));
  hh[4] = __float22half2_rn(make_float2(f2.x, f2.y));
  hh[5] = __float22half2_rn(make_float2(f2.z, f2.w));
  hh[6] = __float22half2_rn(make_float2(f3.x, f3.y));
  hh[7] = __float22half2_rn(make_float2(f3.z, f3.w));
  const uint4* u = (const uint4*)hh;
  csr_a16[2 * (size_t)pos + 0] = u[0];
  csr_a16[2 * (size_t)pos + 1] = u[1];
}

// ================= node linear: h = x @ W_node + b  (8 nodes / 256-thread block) =================
__global__ __launch_bounds__(256) void k_node_linear(
    const float* __restrict__ x, const float* __restrict__ W,
    const float* __restrict__ b, float* __restrict__ h, __half* __restrict__ h16) {
  __shared__ float xs[8][F_IN];              // 2 KB
  int i0 = blockIdx.x * 8;
  ((float2*)xs)[threadIdx.x] = ((const float2*)(x + (size_t)i0 * F_IN))[threadIdx.x];
  __syncthreads();
  int c = threadIdx.x & (H - 1);
  int j0 = (threadIdx.x >> 7) * 4;           // 0 or 4
  float bc = b[c];
  float acc[4] = {bc, bc, bc, bc};
#pragma unroll 8
  for (int k = 0; k < F_IN; ++k) {
    float wv = W[k * H + c];                 // coalesced, L1-hot
#pragma unroll
    for (int j = 0; j < 4; ++j) acc[j] = fmaf(xs[j0 + j][k], wv, acc[j]);  // LDS broadcast
  }
#pragma unroll
  for (int j = 0; j < 4; ++j) {
    size_t idx = (size_t)(i0 + j0 + j) * H + c;
    h[idx] = acc[j];
    h16[idx] = __float2half_rn(acc[j]);
  }
}

// ================= gather: sum[i] = h[i] + sum_in relu(h16[src] + a16@We + be) =================
// 1 wave per node; lane owns channels {2*lane, 2*lane+1}; We columns (16 float2) in registers.
__device__ __forceinline__ float2 edge_mlp(uint4 a0, uint4 a1,
                                           const float2* __restrict__ w2, float2 t) {
  const __half2* pa = (const __half2*)&a0;
  const __half2* pb = (const __half2*)&a1;
#pragma unroll
  for (int j = 0; j < 4; ++j) {
    float2 f = __half22float2(pa[j]);
    t.x = fmaf(f.x, w2[2 * j].x, t.x);     t.y = fmaf(f.x, w2[2 * j].y, t.y);
    t.x = fmaf(f.y, w2[2 * j + 1].x, t.x); t.y = fmaf(f.y, w2[2 * j + 1].y, t.y);
  }
#pragma unroll
  for (int j = 0; j < 4; ++j) {
    float2 f = __half22float2(pb[j]);
    t.x = fmaf(f.x, w2[8 + 2 * j].x, t.x);     t.y = fmaf(f.x, w2[8 + 2 * j].y, t.y);
    t.x = fmaf(f.y, w2[8 + 2 * j + 1].x, t.x); t.y = fmaf(f.y, w2[8 + 2 * j + 1].y, t.y);
  }
  return t;
}

__global__ __launch_bounds__(256) void k_gather(
    const int* __restrict__ rowptr, const int* __restrict__ deg,
    const int* __restrict__ csr_src, const uint4* __restrict__ csr_a16,
    const __half2* __restrict__ h16, const float* __restrict__ We,
    const float* __restrict__ be, const float* __restrict__ h,
    float* __restrict__ sum) {
  int lane = threadIdx.x & 63;
  int node = (blockIdx.x * 256 + threadIdx.x) >> 6;
  if (node >= N) return;
  float2 w2[F_EDGE];
#pragma unroll
  for (int k = 0; k < F_EDGE; ++k) w2[k] = ((const float2*)(We + k * H))[lane];
  float2 bias = ((const float2*)be)[lane];
  float2 acc = ((const float2*)(h + (size_t)node * H))[lane];   // self term, fp32
  int p0 = rowptr[node];
  int pend = p0 + deg[node];
  int p = p0;
  for (; p + 2 <= pend; p += 2) {
    int s0 = csr_src[p];
    int s1 = csr_src[p + 1];
    __half2 g0 = h16[(size_t)s0 * 64 + lane];   // 128B/wave random (2 lines)
    __half2 g1 = h16[(size_t)s1 * 64 + lane];
    uint4 a00 = csr_a16[2 * (size_t)p + 0];     // sequential 64B/edge stream
    uint4 a01 = csr_a16[2 * (size_t)p + 1];
    uint4 a10 = csr_a16[2 * (size_t)p + 2];
    uint4 a11 = csr_a16[2 * (size_t)p + 3];
    float2 t0 = edge_mlp(a00, a01, w2, bias);
    float2 t1 = edge_mlp(a10, a11, w2, bias);
    float2 gf0 = __half22float2(g0);
    float2 gf1 = __half22float2(g1);
    acc.x += fmaxf(gf0.x + t0.x, 0.f) + fmaxf(gf1.x + t1.x, 0.f);
    acc.y += fmaxf(gf0.y + t0.y, 0.f) + fmaxf(gf1.y + t1.y, 0.f);
  }
  for (; p < pend; ++p) {
    int s = csr_src[p];
    __half2 g = h16[(size_t)s * 64 + lane];
    uint4 a0 = csr_a16[2 * (size_t)p + 0];
    uint4 a1 = csr_a16[2 * (size_t)p + 1];
    float2 t = edge_mlp(a0, a1, w2, bias);
    float2 gf = __half22float2(g);
    acc.x += fmaxf(gf.x + t.x, 0.f);
    acc.y += fmaxf(gf.y + t.y, 0.f);
  }
  ((float2*)sum)[(size_t)node * 64 + lane] = acc;
}

// ================= node update: h = leaky_relu(sum @ W_conv[l] + b)  (8 nodes / block) =================
__global__ __launch_bounds__(256) void k_node_update(
    const float* __restrict__ sum, const float* __restrict__ W,
    const float* __restrict__ b, float* __restrict__ hout, __half* __restrict__ h16) {
  __shared__ float t[8][H];                  // 4 KB
  int i0 = blockIdx.x * 8;
  ((float4*)t)[threadIdx.x] = ((const float4*)(sum + (size_t)i0 * H))[threadIdx.x];
  __syncthreads();
  int c = threadIdx.x & (H - 1);
  int j0 = (threadIdx.x >> 7) * 4;
  float bc = b[c];
  float acc[4] = {bc, bc, bc, bc};
#pragma unroll 8
  for (int k = 0; k < H; ++k) {
    float wv = W[k * H + c];                 // coalesced, L1/L2-hot (64 KB)
#pragma unroll
    for (int j = 0; j < 4; ++j) acc[j] = fmaf(t[j0 + j][k], wv, acc[j]);  // LDS broadcast
  }
#pragma unroll
  for (int j = 0; j < 4; ++j) {
    float a = acc[j];
    a = a >= 0.f ? a : NEG * a;
    size_t idx = (size_t)(i0 + j0 + j) * H + c;
    hout[idx] = a;
    h16[idx] = __float2half_rn(a);
  }
}

// ================= head: skip recomputed; y = (skip+h)@W_head + b; LayerNorm =================
__global__ __launch_bounds__(128) void k_head(
    const float* __restrict__ x, const float* __restrict__ Wn,
    const float* __restrict__ bn, const float* __restrict__ hfin,
    const float* __restrict__ W, const float* __restrict__ b,
    const float* __restrict__ gamma, const float* __restrict__ beta,
    float* __restrict__ out) {
  int c = threadIdx.x;
  int i0 = blockIdx.x * 4;
  __shared__ float xs[4][F_IN];              // 1 KB
  __shared__ float t[4][H];                  // 2 KB
  ((float2*)xs)[threadIdx.x] = ((const float2*)(x + (size_t)i0 * F_IN))[threadIdx.x];
  __syncthreads();
#pragma unroll
  for (int j = 0; j < 4; ++j) {
    float a = bn[c];
#pragma unroll 8
    for (int k = 0; k < F_IN; ++k) a = fmaf(xs[j][k], Wn[k * H + c], a);  // LDS broadcast
    t[j][c] = a + hfin[(size_t)(i0 + j) * H + c];
  }
  __syncthreads();
  float bc = b[c];
  float acc[4] = {bc, bc, bc, bc};
#pragma unroll 8
  for (int k = 0; k < H; ++k) {
    float wv = W[k * H + c];
#pragma unroll
    for (int j = 0; j < 4; ++j) acc[j] = fmaf(t[j][k], wv, acc[j]);
  }
  __shared__ float ls[2][4], ls2[2][4];
  int wid = c >> 6;
#pragma unroll
  for (int j = 0; j < 4; ++j) {
    float s = acc[j], s2 = acc[j] * acc[j];
#pragma unroll
    for (int off = 32; off > 0; off >>= 1) {
      s  += __shfl_down(s, off, 64);
      s2 += __shfl_down(s2, off, 64);
    }
    if ((c & 63) == 0) { ls[wid][j] = s; ls2[wid][j] = s2; }
  }
  __syncthreads();
#pragma unroll
  for (int j = 0; j < 4; ++j) {
    float S  = ls[0][j] + ls[1][j];
    float S2 = ls2[0][j] + ls2[1][j];
    float mu  = S * (1.f / H);
    float var = S2 * (1.f / H) - mu * mu;
    float inv = rsqrtf(var + EPS);
    out[(size_t)(i0 + j) * H + c] = (acc[j] - mu) * inv * gamma[c] + beta[c];
  }
}

extern "C" void kernel_launch(void* const* d_in, const int* in_sizes, int n_in,
                              void* d_out, int out_size, void* d_ws, size_t ws_size,
                              hipStream_t stream) {
  const float* x         = (const float*)d_in[0];
  const float* edge_attr = (const float*)d_in[1];
  const int*   eidx      = (const int*)d_in[2];      // int32 (harness-converted)
  const float* W_node    = (const float*)d_in[3];
  const float* b_node    = (const float*)d_in[4];
  const float* W_edge    = (const float*)d_in[5];
  const float* b_edge    = (const float*)d_in[6];
  const float* W_conv    = (const float*)d_in[7];    // [3,128,128]
  const float* b_conv    = (const float*)d_in[8];    // [3,128]
  const float* W_head    = (const float*)d_in[9];
  const float* b_head    = (const float*)d_in[10];
  const float* gamma     = (const float*)d_in[11];
  const float* beta      = (const float*)d_in[12];
  float* out = (float*)d_out;

  // ---- workspace layout (~136.2 MB) ----
  size_t S = (size_t)N * H;                  // 12.8M floats = 51.2 MB
  float*   h       = (float*)d_ws;           // 51.2 MB
  uint4*   csr_a16 = (uint4*)(h + S);        // 51.2 MB (E x 32B, 16B-aligned)
  __half*  h16     = (__half*)(csr_a16 + 2 * (size_t)E);  // 25.6 MB
  int*     csr_src = (int*)(h16 + S);        // 6.4 MB
  int*     deg     = csr_src + E;
  int*     excl    = deg + N;
  int*     rowptr  = excl + N;
  int*     cursor  = rowptr + N;
  int*     bsum    = cursor + N;
  int*     boff    = bsum + 512;
  float*   sum     = out;                    // d_out doubles as layer scratch

  const int eb = (E + 255) / 256;            // 6250

  // ---- CSR build (once; graph fixed across layers) ----
  k_zero<<<NB, 256, 0, stream>>>(deg, N);
  k_hist<<<eb, 256, 0, stream>>>(eidx, deg);
  k_scan_block<<<NB, 256, 0, stream>>>(deg, excl, bsum);
  k_scan_top<<<1, 512, 0, stream>>>(bsum, boff);
  k_scan_add<<<NB, 256, 0, stream>>>(excl, boff, rowptr, cursor);
  k_scatter<<<eb, 256, 0, stream>>>(eidx, edge_attr, cursor, csr_src, csr_a16);

  // ---- network ----
  k_node_linear<<<N / 8, 256, 0, stream>>>(x, W_node, b_node, h, h16);

  for (int l = 0; l < 3; ++l) {
    k_gather<<<N / 4, 256, 0, stream>>>(rowptr, deg, csr_src, csr_a16,
                                        (const __half2*)h16, W_edge, b_edge, h, sum);
    k_node_update<<<N / 8, 256, 0, stream>>>(
        sum, W_conv + (size_t)l * H * H, b_conv + (size_t)l * H, h, h16);
  }

  k_head<<<N / 4, 128, 0, stream>>>(x, W_node, b_node, h, W_head, b_head, gamma, beta, out);
}